// Round 8
// baseline (1721.286 us; speedup 1.0000x reference)
//
#include <hip/hip_runtime.h>

// Problem: S=512, B=256, I=64, H=512, O=25.
// y depends only on batch row 255 -> compute only that row's recurrence.
//
// rnn_pre : xi[t][h] = x[t,255,:].W_ih[h,:] + b_ih[h] + b_hh[h]; re-inits the
//           exchange buffers (sign=1 = not-ready) every launch.
// rnn_seq : 512 sequential steps h = relu(xi_t + W_hh h_prev) on 16 blocks x
//           256 threads (32 rows/block, W_hh register-resident). Cross-block
//           exchange: the PROVEN agent-scope protocol (787->637us) -- u32
//           words, generation in SIGN BIT (relu => h>=0), double-buffered by
//           s&1, phase=(s>>1)&1, skew<2 invariant, 1 poll-reader per word,
//           adaptive pre-poll delay D. UNCHANGED.
//           Round-8 change: produce path flattened. Lane map (w=tid>>6,
//           l=tid&63): row rloc = w*8+(l>>3), k-chunk kc = l&7. A row's 8
//           chunk-partials live in 8 consecutive lanes -> row sum via 3
//           shfl_xor + 1 shfl route to lanes 0..7 -> per-wave 32B coalesced
//           exchange store. Eliminates part[] LDS, barrier A, the b128
//           finalize and its lgkm wait: exchange store now depends on VALU
//           only. h lives in double-buffered padded LDS [2][8*68] (chunk
//           stride 68 -> chunks on distinct banks, conflict-free b128 FMA
//           reads). ONE lgkm-only barrier per step; it orders all-polls-of-s
//           before any store-of-(s+1), carrying the skew<2 invariant.
// rnn_post: y[t] = h_t . W2^T + b2 (512x25).
//
// Workspace: xh[512*512] (xi, progressively overwritten by hseq: each block
// writes h only over its OWN already-consumed xi rows; strictly ordered),
// hg[2*512] exchange words.

#define S_ 512
#define B_ 256
#define I_ 64
#define H_ 512
#define O_ 25
#define G_ 16   // blocks in rnn_seq
#define R_ 32   // rows per block (H_/G_)
#define PAD_ 68 // padded 64-chunk stride: chunk kc -> bank 4*kc (distinct)
#define PADI(i) ((((i) >> 6) * PAD_) + ((i) & 63))

// lgkm-only barrier: no vmcnt(0) drain -> exchange stores / xi prefetch stay
// in flight across it. sched_barrier(0) fences compiler motion (rule #18).
static __device__ __forceinline__ void wg_barrier_lds() {
  __builtin_amdgcn_sched_barrier(0);
  asm volatile("s_waitcnt lgkmcnt(0)" ::: "memory");
  __builtin_amdgcn_s_barrier();
  __builtin_amdgcn_sched_barrier(0);
}

__global__ __launch_bounds__(256) void rnn_pre(
    const float* __restrict__ x, const float* __restrict__ W_ih,
    const float* __restrict__ b_ih, const float* __restrict__ b_hh,
    float* __restrict__ xh, unsigned* __restrict__ hg) {
  const int t = blockIdx.x;
  const int tid = threadIdx.x;
  const int o = blockIdx.y * 256 + tid;
  if (t == 0 && blockIdx.y == 0) {
    // re-init every launch: no reliance on workspace poison / prior state.
    hg[tid] = 0x80000000u;
    hg[tid + 256] = 0x80000000u;
    hg[tid + 512] = 0x80000000u;
    hg[tid + 768] = 0x80000000u;
  }
  __shared__ float xr[I_];
  if (tid < I_) xr[tid] = x[(t * B_ + (B_ - 1)) * I_ + tid];
  __syncthreads();
  float acc = b_ih[o] + b_hh[o];
  const float4* wp = (const float4*)(W_ih + o * I_);
#pragma unroll
  for (int j = 0; j < I_ / 4; ++j) {
    float4 w4 = wp[j];
    acc += w4.x * xr[4 * j] + w4.y * xr[4 * j + 1] + w4.z * xr[4 * j + 2] +
           w4.w * xr[4 * j + 3];
  }
  xh[t * H_ + o] = acc;
}

__global__ __launch_bounds__(256) void rnn_seq(
    const float* __restrict__ W_hh, float* __restrict__ xh,
    unsigned* hg) {
  const int tid = threadIdx.x;
  const int b = blockIdx.x;
  const int w = tid >> 6;        // wave 0..3
  const int l = tid & 63;        // lane
  const int rr = l >> 3;         // row-group within wave (0..7)
  const int kc = l & 7;          // 64-wide k-chunk (0..7)
  const int own_lo = b * R_;
  const int rloc = w * 8 + rr;           // row within block's 32
  const int grow = own_lo + rloc;        // this thread's W row
  const bool prod = (l < 8);             // lanes 0..7: rows w*8+l
  const int prow = own_lo + w * 8 + l;   // producer's global row (l<8)

  __shared__ __align__(16) float hbuf[2][8 * PAD_];  // dbuf by s&1, padded

  // W_hh register-resident: thread holds W_hh[grow][kc*64 .. kc*64+64).
  float wr[64];
  {
    const float4* wp = (const float4*)(W_hh + grow * H_ + kc * 64);
#pragma unroll
    for (int j = 0; j < 16; ++j) {
      float4 v = wp[j];
      wr[4 * j] = v.x; wr[4 * j + 1] = v.y;
      wr[4 * j + 2] = v.z; wr[4 * j + 3] = v.w;
    }
  }
  for (int n = tid; n < 2 * 8 * PAD_; n += 256) ((float*)hbuf)[n] = 0.0f;

  // xi for step 0 (producer lanes); later steps prefetched under the poll.
  float xiv = prod ? xh[prow] : 0.0f;

  // poll pair: words 2*tid, 2*tid+1; own block's pairs skipped (producers
  // write own rows to LDS directly).
  const bool ownp = (tid >= b * (R_ / 2)) && (tid < (b + 1) * (R_ / 2));
  const unsigned long long sm = 0x8000000080000000ull;
  int D = 16;  // adaptive pre-poll delay, in s_sleep(1) (~64cy) units
  wg_barrier_lds();

  for (int s = 0; s < S_; ++s) {
    const int ps = s & 1;
    // ---- partial dot over this thread's 64-wide chunk (4 ILP chains) ----
    float a0 = 0.f, a1 = 0.f, a2 = 0.f, a3 = 0.f;
    const float4* hp = (const float4*)(&hbuf[ps][kc * PAD_]);
#pragma unroll
    for (int j = 0; j < 16; ++j) {
      float4 hv = hp[j];
      a0 = fmaf(wr[4 * j + 0], hv.x, a0);
      a1 = fmaf(wr[4 * j + 1], hv.y, a1);
      a2 = fmaf(wr[4 * j + 2], hv.z, a2);
      a3 = fmaf(wr[4 * j + 3], hv.w, a3);
    }
    float acc = (a0 + a1) + (a2 + a3);
    // row sum: fold the 8 consecutive lanes of this row-group...
    acc += __shfl_xor(acc, 1);
    acc += __shfl_xor(acc, 2);
    acc += __shfl_xor(acc, 4);
    // ...then route row rr's sum (in lane rr*8) to lane rr (lanes 0..7).
    float rsum = __shfl(acc, 8 * (l & 7), 64);

    const unsigned phase = (unsigned)((s >> 1) & 1);
    unsigned* buf = hg + ps * H_;

    if (prod) {
      float h = fmaxf(rsum + xiv, 0.0f);
      // exchange store FIRST (VALU-only dependency: issues immediately);
      // 8 contiguous words per wave = coalesced 32B store.
      __hip_atomic_store(&buf[prow], __float_as_uint(h) | (phase << 31),
                         __ATOMIC_RELAXED, __HIP_MEMORY_SCOPE_AGENT);
      hbuf[ps ^ 1][PADI(prow)] = h;   // own row -> next step's read buffer
      xh[s * H_ + prow] = h;          // hseq (over consumed xi rows)
    }

    if (s == S_ - 1) break;  // no poll needed after last step

    // prefetch next step's xi (in flight under the poll; used >RTT later)
    if (prod) xiv = xh[(s + 1) * H_ + prow];

    if (!ownp) {
      // phase-aligned first sample (adaptive D), then the PROVEN u64 poll.
      for (int d = 0; d < D; ++d) __builtin_amdgcn_s_sleep(1);
      const unsigned long long ph64 = phase ? sm : 0ull;
      const unsigned long long* ap = (const unsigned long long*)buf + tid;
      unsigned long long v;
      int n = 0;
      do {
        v = __hip_atomic_load(ap, __ATOMIC_RELAXED, __HIP_MEMORY_SCOPE_AGENT);
        ++n;
      } while (((v ^ ph64) & sm) != 0ull);
      float2 hv;
      hv.x = __uint_as_float((unsigned)v & 0x7fffffffu);
      hv.y = __uint_as_float((unsigned)(v >> 32) & 0x7fffffffu);
      *(float2*)(&hbuf[ps ^ 1][PADI(2 * tid)]) = hv;
      // adapt: sampled too early -> push later; on time -> creep earlier.
      if (n > 1) {
        D += 4 * (n - 1);
        if (D > 56) D = 56;
      } else if ((s & 15) == 0 && D > 0) {
        --D;
      }
    }
    // ONE barrier/step: orders all-polls-of-s (and LDS writes) before any
    // store of s+1 -> carries the skew<2 invariant; lgkm-only drain.
    wg_barrier_lds();
  }
}

__global__ __launch_bounds__(256) void rnn_post(
    const float* __restrict__ hseq, const float* __restrict__ W2,
    const float* __restrict__ b2, float* __restrict__ y) {
  const int t = blockIdx.x;
  const int tid = threadIdx.x;
  __shared__ float hl[H_];
  __shared__ float part[256];
  for (int n = tid; n < H_; n += 256) hl[n] = hseq[t * H_ + n];
  __syncthreads();
  const int o = tid >> 3;
  const int seg = tid & 7;
  float acc = 0.0f;
  if (o < O_) {
    const float4* wp = (const float4*)(W2 + o * H_ + seg * 64);
    const float4* hp = (const float4*)(hl + seg * 64);
#pragma unroll
    for (int j = 0; j < 16; ++j) {
      float4 w4 = wp[j];
      float4 h4 = hp[j];
      acc += w4.x * h4.x + w4.y * h4.y + w4.z * h4.z + w4.w * h4.w;
    }
  }
  part[tid] = acc;
  __syncthreads();
  if (tid < O_) {
    float sum = 0.0f;
#pragma unroll
    for (int j = 0; j < 8; ++j) sum += part[tid * 8 + j];
    y[t * O_ + tid] = sum + b2[tid];
  }
}

extern "C" void kernel_launch(void* const* d_in, const int* in_sizes, int n_in,
                              void* d_out, int out_size, void* d_ws, size_t ws_size,
                              hipStream_t stream) {
  const float* x    = (const float*)d_in[0];
  const float* W_ih = (const float*)d_in[1];
  const float* W_hh = (const float*)d_in[2];
  const float* b_ih = (const float*)d_in[3];
  const float* b_hh = (const float*)d_in[4];
  const float* W2   = (const float*)d_in[5];
  const float* b2   = (const float*)d_in[6];
  float* y = (float*)d_out;

  float* xh = (float*)d_ws;                  // [512*512] xi -> hseq (aliased)
  unsigned* hg = (unsigned*)(xh + S_ * H_);  // [2*512] sign-tagged exchange

  rnn_pre<<<dim3(S_, 2), 256, 0, stream>>>(x, W_ih, b_ih, b_hh, xh, hg);
  rnn_seq<<<G_, 256, 0, stream>>>(W_hh, xh, hg);
  rnn_post<<<S_, 256, 0, stream>>>(xh, W2, b2, y);
}